// Round 7
// baseline (64.964 us; speedup 1.0000x reference)
//
#include <hip/hip_runtime.h>
#include <hip/hip_bf16.h>

// Problem constants
#define NB    65536      // batch rows
#define ND    1024       // feature dim (K)
#define NT    64         // trees (N)
#define BK    128        // K-chunk in floats (512B per row per phase: DRAM-page friendly)
#define NCH   (ND / BK)  // 8 chunks
#define ROWS  64         // rows per block (4 waves; wave w owns trees [16w,16w+16))

typedef __attribute__((ext_vector_type(8))) short bf16x8;
typedef __attribute__((ext_vector_type(4))) short bf16x4;
typedef __attribute__((ext_vector_type(4))) float f32x4;

__device__ __forceinline__ short f2bf_s(float f) {
    __hip_bfloat16 h = __float2bfloat16(f);
    return __builtin_bit_cast(short, h);
}

// Raw barrier WITHOUT the compiler's vmcnt(0) drain (T4): LDS ops must be complete
// (in-order lgkmcnt covers our ds_writes and all ds_reads of the handed-over buffer),
// but global->REGISTER loads are private and may float across the barrier.
__device__ __forceinline__ void phase_barrier() {
    asm volatile("s_waitcnt lgkmcnt(0)\n\ts_barrier" ::: "memory");
}

// 256 threads / 4 waves. BK=128: each phase reads a 512B contiguous segment per row
// (vs 256B at BK=64) to halve DRAM page-activate overhead. Double-buffered LDS
// (bf16, XOR-swizzled) + double-buffered staging registers (issue ~2 phases early).
__global__ __launch_bounds__(256, 4) void node_main(const float* __restrict__ x,
                                                    const float* __restrict__ F,
                                                    const float* __restrict__ thr,
                                                    const float* __restrict__ lw,
                                                    float* __restrict__ out) {
    __shared__ __align__(16) __hip_bfloat16 Abuf[2][ROWS * BK];   // 2 x 16 KB

    const int tid  = threadIdx.x;
    const int w    = tid >> 6;
    const int lane = tid & 63;
    const int c    = lane & 15;     // MFMA 16-index: batch row (A) / tree col (B)
    const int g    = lane >> 4;     // k-group
    const long blockRow = (long)blockIdx.x * ROWS;
    const float* xbase = x + blockRow * ND;

    // staging: instruction i covers rows i*8 + srow8; 32 lanes x 16B = full 512B
    // contiguous row-segment per instruction (line- and page-coalesced).
    const int srow8 = tid >> 5;     // 0..7
    const int scol  = tid & 31;     // 16B granule within the 512B row-segment

    // per-lane tree constants (one tree per lane within the wave's 16-tree tile)
    const int   t     = w * 16 + c;
    const float thr_t = thr[t];
    const float w00 = lw[t * 4 + 0], w01 = lw[t * 4 + 1];
    const float w10 = lw[t * 4 + 2], w11 = lw[t * 4 + 3];
    const float* Frow = F + (long)t * ND;   // f32, L2-resident; cvt inline

    f32x4 acc[4];
#pragma unroll
    for (int rt = 0; rt < 4; ++rt) acc[rt] = (f32x4){0.f, 0.f, 0.f, 0.f};

    f32x4 rA0[8], rA1[8];   // two in-flight chunk buffers (32 VGPR each)

    auto load_chunk = [&](int ch, f32x4* rA) {
#pragma unroll
        for (int i = 0; i < 8; ++i) {
            const int r = i * 8 + srow8;
            const f32x4* p = (const f32x4*)(xbase + (long)r * ND + ch * BK + scol * 4);
            rA[i] = __builtin_nontemporal_load(p);   // zero-reuse stream: keep F in L2
        }
    };
    auto stage_write = [&](int buf, const f32x4* rA) {
#pragma unroll
        for (int i = 0; i < 8; ++i) {
            const int r = i * 8 + srow8;
            f32x4 a = rA[i];
            bf16x4 v;
            v[0] = f2bf_s(a[0]); v[1] = f2bf_s(a[1]);
            v[2] = f2bf_s(a[2]); v[3] = f2bf_s(a[3]);
            const int s = (scol >> 1) ^ (r & 7);      // T2 XOR swizzle, 16B slots (0..15)
            char* p = (char*)(&Abuf[buf][0]) + r * 256 + (s << 4) + ((scol & 1) << 3);
            *(bf16x4*)p = v;
        }
    };
    auto compute = [&](int ch, int buf) {
#pragma unroll
        for (int kk = 0; kk < 4; ++kk) {
            // B fragment: inline f32->bf16 (L2-resident)
            const float* fp = Frow + ch * BK + kk * 32 + g * 8;
            f32x4 b0 = *(const f32x4*)(fp);
            f32x4 b1 = *(const f32x4*)(fp + 4);
            bf16x8 bfrag;
            bfrag[0] = f2bf_s(b0[0]); bfrag[1] = f2bf_s(b0[1]);
            bfrag[2] = f2bf_s(b0[2]); bfrag[3] = f2bf_s(b0[3]);
            bfrag[4] = f2bf_s(b1[0]); bfrag[5] = f2bf_s(b1[1]);
            bfrag[6] = f2bf_s(b1[2]); bfrag[7] = f2bf_s(b1[3]);
#pragma unroll
            for (int rt = 0; rt < 4; ++rt) {
                const int r    = rt * 16 + c;
                const int slot = (kk * 4 + g) ^ (r & 7);
                bf16x8 afrag = *(const bf16x8*)(&Abuf[buf][r * BK + slot * 8]);
                acc[rt] = __builtin_amdgcn_mfma_f32_16x16x32_bf16(afrag, bfrag, acc[rt], 0, 0, 0);
            }
        }
    };

    // prologue: chunks 0,1 in flight; stage 0
    load_chunk(0, rA0);
    load_chunk(1, rA1);
    stage_write(0, rA0);
    phase_barrier();

#pragma unroll
    for (int ch2 = 0; ch2 < NCH; ch2 += 2) {
        // ---- even phase: buf0 holds ch2 ----
        if (ch2 + 2 < NCH) load_chunk(ch2 + 2, rA0);   // floats across barriers
        compute(ch2, 0);
        stage_write(1, rA1);                           // rA1 loaded a full phase ago
        phase_barrier();
        // ---- odd phase: buf1 holds ch2+1 ----
        if (ch2 + 3 < NCH) load_chunk(ch2 + 3, rA1);
        compute(ch2 + 1, 1);
        if (ch2 + 2 < NCH) stage_write(0, rA0);
        phase_barrier();
    }

    // ---- epilogue: sigmoid + leaf combine + tree reduction ----
    float* partials = (float*)(&Abuf[0][0]);   // aliased; safe after last phase_barrier
#pragma unroll
    for (int rt = 0; rt < 4; ++rt) {
#pragma unroll
        for (int reg = 0; reg < 4; ++reg) {
            const float logit = acc[rt][reg] - thr_t;
            const float p = 1.0f / (1.0f + __expf(-logit));
            float o0 = w10 + p * (w00 - w10);
            float o1 = w11 + p * (w01 - w11);
#pragma unroll
            for (int m = 1; m < 16; m <<= 1) {   // butterfly over 16 trees (c bits)
                o0 += __shfl_xor(o0, m, 64);
                o1 += __shfl_xor(o1, m, 64);
            }
            if (c == 0) {
                const int row = rt * 16 + g * 4 + reg;
                partials[(w * ROWS + row) * 2 + 0] = o0;
                partials[(w * ROWS + row) * 2 + 1] = o1;
            }
        }
    }
    __syncthreads();
    if (tid < 128) {
        const int row = tid >> 1, o = tid & 1;
        const float s = partials[(0 * ROWS + row) * 2 + o] + partials[(1 * ROWS + row) * 2 + o] +
                        partials[(2 * ROWS + row) * 2 + o] + partials[(3 * ROWS + row) * 2 + o];
        out[(blockRow + row) * 2 + o] = s;
    }
}

extern "C" void kernel_launch(void* const* d_in, const int* in_sizes, int n_in,
                              void* d_out, int out_size, void* d_ws, size_t ws_size,
                              hipStream_t stream) {
    const float* x   = (const float*)d_in[0];
    const float* fs  = (const float*)d_in[1];
    const float* thr = (const float*)d_in[2];
    const float* lw  = (const float*)d_in[3];
    float* out = (float*)d_out;
    (void)in_sizes; (void)n_in; (void)out_size; (void)d_ws; (void)ws_size;

    node_main<<<NB / ROWS, 256, 0, stream>>>(x, fs, thr, lw, out);
}